// Round 15
// baseline (270.907 us; speedup 1.0000x reference)
//
#include <hip/hip_runtime.h>
#include <hip/hip_bf16.h>

// L=2048, E=512, E_PT=300, H=16. All inputs f32. Output f32 [2048,512].
//
// R15 = R14 (proven 268us) + three deltas:
//  - gram: 64x32 tiles / 128 threads (2 waves x 32x32 quadrant): 1056 live
//    blocks = 4.1/CU (vs 2.06), 2x finer barrier domains, ds_read 0.125 B/MAC
//    (LDS floor 31->25us). Per-element mirror w/ plain stores (bit-identical).
//  - softmax + label-cast + W0/W1-transpose merged into one post_kernel;
//    GCN temporaries moved to the dead [8.39MB,17.8MB) window (no S alias).
//  - bl_count moved OUT of live Y (was memset inside Y -> benign corruption).
// 15 -> 12 dispatches. GCN gemms = R14's proven template, unchanged.

typedef __attribute__((ext_vector_type(8))) short bf16x8;
typedef __attribute__((ext_vector_type(4))) float f32x4;

#define L_DIM 2048
#define EPT 300
#define H_DIM 16
#define KDIM 4800
#define WINDOW 5.5e-4f
#define LIST_CAP 2500000

// ---------------- 1) Y + norms ----------------
__global__ void compute_y_kernel(const float* __restrict__ xpt,
                                 const float* __restrict__ Wpt,
                                 __hip_bfloat16* __restrict__ Y,
                                 float* __restrict__ norms) {
  int gw = (blockIdx.x * 256 + threadIdx.x) >> 6;  // wave id = (i,h) pair
  int lane = threadIdx.x & 63;
  int i = gw >> 4, h = gw & 15;
  const float* x = xpt + i * EPT;
  const float* w = Wpt + h * EPT;
  float v[5];
  float ss = 0.f;
#pragma unroll
  for (int t = 0; t < 5; ++t) {
    int e = lane + 64 * t;
    float val = 0.f;
    if (e < EPT) {
      float we = w[e];
      val = x[e] * we * we;
    }
    v[t] = val;
    ss += val * val;
  }
#pragma unroll
  for (int o = 32; o >= 1; o >>= 1) ss += __shfl_xor(ss, o, 64);
  float n = fmaxf(sqrtf(ss), 1e-12f);
  if (lane == 0) norms[i * H_DIM + h] = n;
  float scale = 0.25f / n;  // 1/(norm*sqrt(H))
#pragma unroll
  for (int t = 0; t < 5; ++t) {
    int e = lane + 64 * t;
    if (e < EPT) Y[(size_t)i * KDIM + h * EPT + e] = __float2bfloat16(v[t] * scale);
  }
}

// ------------- 2) gram: S = Y Y^T, 64x32 tiles, 128 threads ------------------
// 2 waves, each one 32x32 quadrant. Triangle skip (col0+32 <= row0) +
// per-element mirror (plain stores; duplicate writes are bit-identical).
__global__ __launch_bounds__(128) void gram_kernel(const __hip_bfloat16* __restrict__ Y,
                                                   float* __restrict__ S) {
  const int row0 = blockIdx.y * 64, col0 = blockIdx.x * 32;
  if (col0 + 32 <= row0) return;  // fully below diagonal
  __shared__ __attribute__((aligned(16))) __hip_bfloat16 As[2][64 * 64];
  __shared__ __attribute__((aligned(16))) __hip_bfloat16 Bs[2][32 * 64];
  const int tid = threadIdx.x;  // 0..127
  const int lane = tid & 63;
  const int wave = tid >> 6;    // 0..1
  const int r = lane & 15, q = lane >> 4;
  const int srow = tid >> 3;    // 0..15
  const int schunk = (tid & 7) ^ (srow & 7);

  f32x4 acc[2][2];
#pragma unroll
  for (int a = 0; a < 2; ++a)
#pragma unroll
    for (int b = 0; b < 2; ++b) {
      f32x4 z = {0.f, 0.f, 0.f, 0.f};
      acc[a][b] = z;
    }
  const int niter = KDIM >> 6;  // 75

#define GSTAGE(bufi, k0)                                                                      \
  {                                                                                           \
    _Pragma("unroll") for (int it = 0; it < 4; ++it) {                                        \
      __builtin_amdgcn_global_load_lds(                                                       \
          (const __attribute__((address_space(1))) void*)(Y + (size_t)(row0 + it * 16 + srow) * KDIM + \
                                                          (k0) + schunk * 8),                 \
          (__attribute__((address_space(3))) void*)(&As[bufi][(it * 128 + tid) * 8]), 16, 0, 0); \
    }                                                                                         \
    _Pragma("unroll") for (int it = 0; it < 2; ++it) {                                        \
      __builtin_amdgcn_global_load_lds(                                                       \
          (const __attribute__((address_space(1))) void*)(Y + (size_t)(col0 + it * 16 + srow) * KDIM + \
                                                          (k0) + schunk * 8),                 \
          (__attribute__((address_space(3))) void*)(&Bs[bufi][(it * 128 + tid) * 8]), 16, 0, 0); \
    }                                                                                         \
  }

  GSTAGE(0, 0)
  for (int k = 0; k < niter; ++k) {
    __syncthreads();
    if (k + 1 < niter) GSTAGE((k + 1) & 1, (k + 1) << 6)
    const __hip_bfloat16* as = As[k & 1];
    const __hip_bfloat16* bs = Bs[k & 1];
#pragma unroll
    for (int kk = 0; kk < 2; ++kk) {
      const int ch = ((kk * 4 + q) ^ (r & 7)) * 8;
      bf16x8 af[2], bfr[2];
#pragma unroll
      for (int t = 0; t < 2; ++t)
        af[t] = *(const bf16x8*)(as + (wave * 32 + t * 16 + r) * 64 + ch);
#pragma unroll
      for (int c = 0; c < 2; ++c)
        bfr[c] = *(const bf16x8*)(bs + (c * 16 + r) * 64 + ch);
#pragma unroll
      for (int tm = 0; tm < 2; ++tm)
#pragma unroll
        for (int tn = 0; tn < 2; ++tn)
          acc[tm][tn] = __builtin_amdgcn_mfma_f32_16x16x32_bf16(af[tm], bfr[tn], acc[tm][tn], 0, 0, 0);
    }
  }
#undef GSTAGE
  // C/D: col = lane&15, row = (lane>>4)*4 + reg
#pragma unroll
  for (int tm = 0; tm < 2; ++tm) {
    int gr0 = row0 + wave * 32 + tm * 16 + q * 4;
#pragma unroll
    for (int tn = 0; tn < 2; ++tn) {
      int gc = col0 + tn * 16 + r;
#pragma unroll
      for (int p = 0; p < 4; ++p) {
        float vv = acc[tm][tn][p];
        int gr = gr0 + p;
        S[(size_t)gr * L_DIM + gc] = vv;
        if (gc > gr) S[(size_t)gc * L_DIM + gr] = vv;  // mirror (bit-identical)
      }
    }
  }
}

// ---------------- 3) bt-GEMM: C = A * B^T (R14-proven, unchanged) ------------
template <int BM, int BN, bool RELU, bool OUT_BF16, bool SPLITX>
__global__ __launch_bounds__(256) void gemm_bt(const __hip_bfloat16* __restrict__ A,
                                               const __hip_bfloat16* __restrict__ B,
                                               void* __restrict__ C0v, void* __restrict__ C1v,
                                               int M, int N, int K) {
  constexpr int WMG = BM / 64;
  constexpr int WNG = 4 / WMG;
  constexpr int NC = BN / (16 * WNG);
  int bx = blockIdx.x;
  int kbeg = 0, kend = K;
  if (SPLITX) {
    const int xhalf = gridDim.x >> 1;
    const int khalf = ((K >> 1) + 63) & ~63;
    if (bx >= xhalf) {
      bx -= xhalf;
      kbeg = khalf;
    } else {
      kend = khalf;
    }
  }
  const int row0 = blockIdx.y * BM, col0 = bx * BN;
  __shared__ __attribute__((aligned(16))) __hip_bfloat16 As[2][BM * 64];
  __shared__ __attribute__((aligned(16))) __hip_bfloat16 Bs[2][BN * 64];
  const int tid = threadIdx.x;
  const int lane = tid & 63;
  const int wave = tid >> 6;
  const int wm = wave / WNG, wn = wave % WNG;
  const int r = lane & 15, q = lane >> 4;
  const int srow = tid >> 3;
  const int schunk = (tid & 7) ^ (srow & 7);

  f32x4 acc[4][NC];
#pragma unroll
  for (int a = 0; a < 4; ++a)
#pragma unroll
    for (int b = 0; b < NC; ++b) {
      f32x4 z = {0.f, 0.f, 0.f, 0.f};
      acc[a][b] = z;
    }

  const int niter = (kend - kbeg) >> 6;

#define STAGE(bufi, k0)                                                                       \
  {                                                                                           \
    _Pragma("unroll") for (int it = 0; it < BM / 32; ++it) {                                  \
      __builtin_amdgcn_global_load_lds(                                                       \
          (const __attribute__((address_space(1))) void*)(A + (size_t)(row0 + it * 32 + srow) * K + \
                                                          (k0) + schunk * 8),                 \
          (__attribute__((address_space(3))) void*)(&As[bufi][(it * 256 + tid) * 8]), 16, 0, 0); \
    }                                                                                         \
    _Pragma("unroll") for (int it = 0; it < BN / 32; ++it) {                                  \
      __builtin_amdgcn_global_load_lds(                                                       \
          (const __attribute__((address_space(1))) void*)(B + (size_t)(col0 + it * 32 + srow) * K + \
                                                          (k0) + schunk * 8),                 \
          (__attribute__((address_space(3))) void*)(&Bs[bufi][(it * 256 + tid) * 8]), 16, 0, 0); \
    }                                                                                         \
  }

  STAGE(0, kbeg)
  for (int k = 0; k < niter; ++k) {
    __syncthreads();
    if (k + 1 < niter) STAGE((k + 1) & 1, kbeg + ((k + 1) << 6))
    const __hip_bfloat16* as = As[k & 1];
    const __hip_bfloat16* bs = Bs[k & 1];
#pragma unroll
    for (int kk = 0; kk < 2; ++kk) {
      const int ch = ((kk * 4 + q) ^ (r & 7)) * 8;
      bf16x8 af[4], bfr[NC];
#pragma unroll
      for (int t = 0; t < 4; ++t)
        af[t] = *(const bf16x8*)(as + (wm * 64 + t * 16 + r) * 64 + ch);
#pragma unroll
      for (int c = 0; c < NC; ++c)
        bfr[c] = *(const bf16x8*)(bs + (wn * 16 * NC + c * 16 + r) * 64 + ch);
#pragma unroll
      for (int tm = 0; tm < 4; ++tm)
#pragma unroll
        for (int tn = 0; tn < NC; ++tn)
          acc[tm][tn] = __builtin_amdgcn_mfma_f32_16x16x32_bf16(af[tm], bfr[tn], acc[tm][tn], 0, 0, 0);
    }
  }
#undef STAGE
  float* dst = (float*)(SPLITX ? (kbeg > 0 ? C1v : C0v) : C0v);
#pragma unroll
  for (int tm = 0; tm < 4; ++tm) {
    int gr0 = row0 + wm * 64 + tm * 16 + q * 4;
#pragma unroll
    for (int tn = 0; tn < NC; ++tn) {
      int gc = col0 + wn * 16 * NC + tn * 16 + r;
#pragma unroll
      for (int p = 0; p < 4; ++p) {
        float vv = acc[tm][tn][p];
        if (RELU) vv = fmaxf(vv, 0.f);
        if (OUT_BF16)
          ((__hip_bfloat16*)C0v)[(size_t)(gr0 + p) * N + gc] = __float2bfloat16(vv);
        else
          dst[(size_t)(gr0 + p) * N + gc] = vv;
      }
    }
  }
}

// ---------------- 4a) scan upper triangle, per-block LDS compaction ----------
__global__ __launch_bounds__(256) void scan_borderline(const float* __restrict__ S,
                                                       int* __restrict__ count,
                                                       int* __restrict__ list) {
  __shared__ int lqueue[2048];
  __shared__ int lcount;
  __shared__ int gbase;
  if (threadIdx.x == 0) lcount = 0;
  __syncthreads();
  const int row = blockIdx.x;
  const int base_idx = row * 2048;
#pragma unroll
  for (int t = 0; t < 2; ++t) {
    int idx = base_idx + t * 1024 + threadIdx.x * 4;
    float4 v = *(const float4*)(S + idx);
    float vv[4] = {v.x, v.y, v.z, v.w};
#pragma unroll
    for (int u = 0; u < 4; ++u) {
      int j = (idx + u) & 2047;
      if (j >= row && fabsf(vv[u] - 0.1f) < WINDOW) {
        int p = atomicAdd(&lcount, 1);  // LDS atomic
        lqueue[p] = idx + u;
      }
    }
  }
  __syncthreads();
  if (threadIdx.x == 0) gbase = atomicAdd(count, lcount);
  __syncthreads();
  int n = lcount, g0 = gbase;
  for (int k = threadIdx.x; k < n; k += 256) {
    int pos = g0 + k;
    if (pos < LIST_CAP) list[pos] = lqueue[k];
  }
}

// ---------------- 4b) exact f32 repair, pipelined xj prefetch ----------------
__global__ void repair_borderline(float* __restrict__ S, const int* __restrict__ count,
                                  const int* __restrict__ list, const float* __restrict__ xpt,
                                  const float* __restrict__ Wpt, const float* __restrict__ norms) {
  const int lane = threadIdx.x & 63;
  const int wid = (blockIdx.x * 256 + threadIdx.x) >> 6;
  const int nw = gridDim.x * 4;
  int n = *count;
  if (n > LIST_CAP) n = LIST_CAP;
  const int chunk = (n + nw - 1) / nw;
  int k0 = wid * chunk;
  int k1 = k0 + chunk < n ? k0 + chunk : n;
  if (k0 >= k1) return;
  int e = list[k0];
  int i = e >> 11, j = e & 2047;
  float xiv[5], xjv[5];
  {
    const float* xi = xpt + i * EPT;
    const float* xj = xpt + j * EPT;
#pragma unroll
    for (int t = 0; t < 5; ++t) {
      int idx = lane + 64 * t;
      xiv[t] = idx < EPT ? xi[idx] : 0.f;
      xjv[t] = idx < EPT ? xj[idx] : 0.f;
    }
  }
  int cur_i = i;
  for (int k = k0; k < k1; ++k) {
    int en = (k + 1 < k1) ? list[k + 1] : e;
    int in2 = en >> 11, jn = en & 2047;
    const float* xjp = xpt + jn * EPT;
    float xjn[5];
#pragma unroll
    for (int t = 0; t < 5; ++t) {
      int idx = lane + 64 * t;
      xjn[t] = idx < EPT ? xjp[idx] : 0.f;
    }
    float pre[5];
#pragma unroll
    for (int t = 0; t < 5; ++t) pre[t] = xiv[t] * xjv[t];
    float accv = 0.f;
#pragma unroll
    for (int h = 0; h < H_DIM; ++h) {
      float ph = 0.f;
#pragma unroll
      for (int t = 0; t < 5; ++t) {
        int idx = lane + 64 * t;
        if (idx < EPT) {
          float w = Wpt[h * EPT + idx];
          float w2 = w * w;
          ph += pre[t] * (w2 * w2);  // w^4 inline
        }
      }
      float invn = 1.f / (norms[i * H_DIM + h] * norms[j * H_DIM + h]);
      accv += ph * invn;
    }
#pragma unroll
    for (int o = 32; o >= 1; o >>= 1) accv += __shfl_xor(accv, o, 64);
    if (lane == 0) {
      float val = accv * (1.f / 16.f);
      S[(size_t)i * L_DIM + j] = val;
      S[(size_t)j * L_DIM + i] = val;  // symmetric twin
    }
    if (in2 != cur_i) {
      const float* xi = xpt + in2 * EPT;
#pragma unroll
      for (int t = 0; t < 5; ++t) {
        int idx = lane + 64 * t;
        xiv[t] = idx < EPT ? xi[idx] : 0.f;
      }
      cur_i = in2;
    }
    i = in2;
    j = jn;
    e = en;
#pragma unroll
    for (int t = 0; t < 5; ++t) xjv[t] = xjn[t];
  }
}

// ------- 5) post: softmax->adj  +  label cast  +  W0/W1 transpose -----------
// grid 6656: [0,2048) softmax rows; [2048,6144) cast; [6144,6656) transpose.
__global__ __launch_bounds__(256) void post_kernel(const float* __restrict__ S,
                                                   __hip_bfloat16* __restrict__ adj,
                                                   const float* __restrict__ label,
                                                   __hip_bfloat16* __restrict__ Lbf,
                                                   const float* __restrict__ W0,
                                                   const float* __restrict__ W1,
                                                   __hip_bfloat16* __restrict__ W0t,
                                                   __hip_bfloat16* __restrict__ W1t) {
  __shared__ float red[4];
  __shared__ float tile[32][33];
  const int b = blockIdx.x;
  const int tid = threadIdx.x;
  if (b < 2048) {
    const int row = b;
    const float* s = S + (size_t)row * L_DIM;
    float m = -1e30f;
    for (int j = tid; j < L_DIM; j += 256) {
      float v = s[j];
      if (v >= 0.1f && v > m) m = v;
    }
#pragma unroll
    for (int o = 32; o >= 1; o >>= 1) m = fmaxf(m, __shfl_xor(m, o, 64));
    if ((tid & 63) == 0) red[tid >> 6] = m;
    __syncthreads();
    m = fmaxf(fmaxf(red[0], red[1]), fmaxf(red[2], red[3]));
    float sum = 0.f;
    for (int j = tid; j < L_DIM; j += 256) {
      float v = s[j];
      if (v >= 0.1f) sum += __expf(v - m);
    }
#pragma unroll
    for (int o = 32; o >= 1; o >>= 1) sum += __shfl_xor(sum, o, 64);
    __syncthreads();
    if ((tid & 63) == 0) red[tid >> 6] = sum;
    __syncthreads();
    sum = red[0] + red[1] + red[2] + red[3];
    float inv = 1.f / sum;
    for (int j = tid; j < L_DIM; j += 256) {
      float v = s[j];
      float a = (v >= 0.1f) ? __expf(v - m) * inv : 0.f;
      adj[(size_t)row * L_DIM + j] = __float2bfloat16(a);
    }
    return;
  }
  if (b < 6144) {
    int i = (b - 2048) * 256 + tid;
    Lbf[i] = __float2bfloat16(label[i]);
    return;
  }
  // transpose: local in [0,512); first 256 -> W0
  int local = b - 6144;
  const bool first = local < 256;
  const float* src = first ? W0 : W1;
  __hip_bfloat16* dst = first ? W0t : W1t;
  int rem = local & 255;
  int c0 = (rem & 15) * 32, r0 = (rem >> 4) * 32;
  int tx = tid & 31, ty = tid >> 5;
  for (int i2 = ty; i2 < 32; i2 += 8) tile[i2][tx] = src[(size_t)(r0 + i2) * 512 + c0 + tx];
  __syncthreads();
  for (int i2 = ty; i2 < 32; i2 += 8)
    dst[(size_t)(c0 + i2) * 512 + r0 + tx] = __float2bfloat16(tile[tx][i2]);
}

// ---------------- split-K combiners (R14-proven) ----------------
__global__ void combine_relu_bf16(const float* __restrict__ P0, const float* __restrict__ P1,
                                  __hip_bfloat16* __restrict__ X) {
  int i = blockIdx.x * 256 + threadIdx.x;
  float4 a = ((const float4*)P0)[i];
  float4 b = ((const float4*)P1)[i];
  __hip_bfloat16 o0 = __float2bfloat16(fmaxf(a.x + b.x, 0.f));
  __hip_bfloat16 o1 = __float2bfloat16(fmaxf(a.y + b.y, 0.f));
  __hip_bfloat16 o2 = __float2bfloat16(fmaxf(a.z + b.z, 0.f));
  __hip_bfloat16 o3 = __float2bfloat16(fmaxf(a.w + b.w, 0.f));
  X[4 * i + 0] = o0;
  X[4 * i + 1] = o1;
  X[4 * i + 2] = o2;
  X[4 * i + 3] = o3;
}

__global__ void combine_relu_f32(const float* __restrict__ P0, const float* __restrict__ P1,
                                 float* __restrict__ X) {
  int i = blockIdx.x * 256 + threadIdx.x;
  float4 a = ((const float4*)P0)[i];
  float4 b = ((const float4*)P1)[i];
  float4 v;
  v.x = fmaxf(a.x + b.x, 0.f);
  v.y = fmaxf(a.y + b.y, 0.f);
  v.z = fmaxf(a.z + b.z, 0.f);
  v.w = fmaxf(a.w + b.w, 0.f);
  ((float4*)X)[i] = v;
}

extern "C" void kernel_launch(void* const* d_in, const int* in_sizes, int n_in, void* d_out,
                              int out_size, void* d_ws, size_t ws_size, hipStream_t stream) {
  const float* label = (const float*)d_in[0];  // [2048,512]
  const float* xpt = (const float*)d_in[1];    // [2048,300]
  const float* Wpt = (const float*)d_in[2];    // [16,300]
  const float* W0 = (const float*)d_in[3];     // [512,512]
  const float* W1 = (const float*)d_in[4];     // [512,512]
  float* out = (float*)d_out;                  // [2048,512]

  // ---- layout (peak 44.96MB; ws >= 53.4MB proven by R12's split run) ----
  char* ws = (char*)d_ws;
  __hip_bfloat16* Y = (__hip_bfloat16*)ws;              // [0, 19,660,800) live thru gram
  float* S = (float*)(ws + 19660800);                   // [19,660,800, 36,438,016)
  float* norms = (float*)(ws + 36438016);               // 128KB -> ends 36,569,088
  float* P0 = (float*)(ws + 36569088);                  // 4MB partial
  float* P1 = (float*)(ws + 40763392);                  // 4MB -> ends 44,957,696
  int* bl_count = (int*)(ws + 44957696);                // OUTSIDE live Y (R14 bug fixed)
  int* bl_list = (int*)(ws + 9437696);                  // dead-Y region, written post-gram
  __hip_bfloat16* adj = (__hip_bfloat16*)ws;            // [0, 8,388,608) after softmax
  // GCN temporaries in the dead [8.39MB, 19.66MB) window (NOT S: post_kernel
  // reads S for softmax while writing these):
  __hip_bfloat16* Lbf = (__hip_bfloat16*)(ws + 8388608);    // wait—overlaps bl_list? see below
  // bl_list [9,437,696, 19,437,696) is dead once repair finishes; post_kernel
  // runs after repair, so reuse is safe. Lbf placed at 8,388,608 (2MB) spills
  // into bl_list's region only past 9,437,696 — post-repair, fine.
  __hip_bfloat16* W0t = (__hip_bfloat16*)(ws + 10485760);   // 0.5MB
  __hip_bfloat16* W1t = (__hip_bfloat16*)(ws + 11010048);   // 0.5MB
  __hip_bfloat16* T0t = (__hip_bfloat16*)(ws + 11534336);   // 2MB [512x2048]
  __hip_bfloat16* X1 = (__hip_bfloat16*)(ws + 13631488);    // 2MB [2048x512]
  __hip_bfloat16* T1t = (__hip_bfloat16*)(ws + 15728640);   // 2MB -> ends 17,825,792

  compute_y_kernel<<<8192, 256, 0, stream>>>(xpt, Wpt, Y, norms);
  hipMemsetAsync(bl_count, 0, 4, stream);
  // S = Y Y^T: 64x32 tiles, 1056 live blocks, per-element mirror
  gram_kernel<<<dim3(64, 32), 128, 0, stream>>>(Y, S);
  scan_borderline<<<2048, 256, 0, stream>>>(S, bl_count, bl_list);
  repair_borderline<<<2048, 256, 0, stream>>>(S, bl_count, bl_list, xpt, Wpt, norms);
  // softmax -> adj + label cast + W transposes (one launch; S still live here)
  post_kernel<<<6656, 256, 0, stream>>>(S, adj, label, Lbf, W0, W1, W0t, W1t);
  // T0t = (label@W0)^T = W0t * Lbf^T   [512 x 2048]
  gemm_bt<64, 64, false, true, false><<<dim3(32, 8), 256, 0, stream>>>(W0t, Lbf, T0t, nullptr, 512, 2048, 512);
  // X1 = relu(adj @ T0): split-K=2 (x-folded, 512 blocks) -> P0/P1, combine
  gemm_bt<64, 64, false, false, true><<<dim3(16, 32), 256, 0, stream>>>(adj, T0t, P0, P1, 2048, 512, 2048);
  combine_relu_bf16<<<1024, 256, 0, stream>>>(P0, P1, X1);
  // T1t = (X1@W1)^T = W1t * X1^T   [512 x 2048]
  gemm_bt<64, 64, false, true, false><<<dim3(32, 8), 256, 0, stream>>>(W1t, X1, T1t, nullptr, 512, 2048, 512);
  // out = relu(adj @ T1): split-K=2 -> P0/P1, combine into d_out
  gemm_bt<64, 64, false, false, true><<<dim3(16, 32), 256, 0, stream>>>(adj, T1t, P0, P1, 2048, 512, 2048);
  combine_relu_f32<<<1024, 256, 0, stream>>>(P0, P1, out);
}

// Round 16
// 261.472 us; speedup vs baseline: 1.0361x; 1.0361x over previous
//
#include <hip/hip_runtime.h>
#include <hip/hip_bf16.h>

// L=2048, E=512, E_PT=300, H=16. All inputs f32. Output f32 [2048,512].
//
// R16 = best-of merge:
//  - gram: R14-proven gemm_bt 64x64 triangle+mirror, grid(32,32), 256 thr
//    (R15's 128-thr 64x32 falsified: worse MFMA:ds_read ratio, +6MB FETCH,
//    12% occ -> 99us. 63us/528-block config is this structure's optimum;
//    every perturbation tried — split-K, swizzle, tile reshape — regressed.)
//  - R15's post_kernel fusion + layout + bl_count fix kept (R15 passed;
//    prep1-style fusion isolated as the R6/R7 crash suspect, stays out).
//  - scan: skip float4 groups fully below the diagonal (~45% less S read).

typedef __attribute__((ext_vector_type(8))) short bf16x8;
typedef __attribute__((ext_vector_type(4))) float f32x4;

#define L_DIM 2048
#define EPT 300
#define H_DIM 16
#define KDIM 4800
#define WINDOW 5.5e-4f
#define LIST_CAP 2500000

// ---------------- 1) Y + norms ----------------
__global__ void compute_y_kernel(const float* __restrict__ xpt,
                                 const float* __restrict__ Wpt,
                                 __hip_bfloat16* __restrict__ Y,
                                 float* __restrict__ norms) {
  int gw = (blockIdx.x * 256 + threadIdx.x) >> 6;  // wave id = (i,h) pair
  int lane = threadIdx.x & 63;
  int i = gw >> 4, h = gw & 15;
  const float* x = xpt + i * EPT;
  const float* w = Wpt + h * EPT;
  float v[5];
  float ss = 0.f;
#pragma unroll
  for (int t = 0; t < 5; ++t) {
    int e = lane + 64 * t;
    float val = 0.f;
    if (e < EPT) {
      float we = w[e];
      val = x[e] * we * we;
    }
    v[t] = val;
    ss += val * val;
  }
#pragma unroll
  for (int o = 32; o >= 1; o >>= 1) ss += __shfl_xor(ss, o, 64);
  float n = fmaxf(sqrtf(ss), 1e-12f);
  if (lane == 0) norms[i * H_DIM + h] = n;
  float scale = 0.25f / n;  // 1/(norm*sqrt(H))
#pragma unroll
  for (int t = 0; t < 5; ++t) {
    int e = lane + 64 * t;
    if (e < EPT) Y[(size_t)i * KDIM + h * EPT + e] = __float2bfloat16(v[t] * scale);
  }
}

// ---------------- 2) bt-GEMM: C = A * B^T (R14-proven) ----------------
// A: [M,K] bf16 rm, B: [N,K] bf16 rm. XOR-swizzled LDS, double-buffered.
// SPLITX: gridDim.x folds 2 K-halves; half0 -> C0, half1 -> C1 (plain stores).
// MIRROR: skip fully-below-diagonal blocks; mirror-write strictly-upper only.
template <int BM, int BN, bool RELU, bool OUT_BF16, bool MIRROR, bool SPLITX>
__global__ __launch_bounds__(256) void gemm_bt(const __hip_bfloat16* __restrict__ A,
                                               const __hip_bfloat16* __restrict__ B,
                                               void* __restrict__ C0v, void* __restrict__ C1v,
                                               int M, int N, int K) {
  constexpr int WMG = BM / 64;
  constexpr int WNG = 4 / WMG;
  constexpr int NC = BN / (16 * WNG);
  int bx = blockIdx.x;
  int kbeg = 0, kend = K;
  if (SPLITX) {
    const int xhalf = gridDim.x >> 1;
    const int khalf = ((K >> 1) + 63) & ~63;
    if (bx >= xhalf) {
      bx -= xhalf;
      kbeg = khalf;
    } else {
      kend = khalf;
    }
  }
  const int row0 = blockIdx.y * BM, col0 = bx * BN;
  if (MIRROR && col0 + BN <= row0) return;  // fully below diagonal
  const bool do_mirror = MIRROR && (col0 > row0);
  __shared__ __attribute__((aligned(16))) __hip_bfloat16 As[2][BM * 64];
  __shared__ __attribute__((aligned(16))) __hip_bfloat16 Bs[2][BN * 64];
  const int tid = threadIdx.x;
  const int lane = tid & 63;
  const int wave = tid >> 6;
  const int wm = wave / WNG, wn = wave % WNG;
  const int r = lane & 15, q = lane >> 4;
  const int srow = tid >> 3;
  const int schunk = (tid & 7) ^ (srow & 7);

  f32x4 acc[4][NC];
#pragma unroll
  for (int a = 0; a < 4; ++a)
#pragma unroll
    for (int b = 0; b < NC; ++b) {
      f32x4 z = {0.f, 0.f, 0.f, 0.f};
      acc[a][b] = z;
    }

  const int niter = (kend - kbeg) >> 6;

#define STAGE(bufi, k0)                                                                       \
  {                                                                                           \
    _Pragma("unroll") for (int it = 0; it < BM / 32; ++it) {                                  \
      __builtin_amdgcn_global_load_lds(                                                       \
          (const __attribute__((address_space(1))) void*)(A + (size_t)(row0 + it * 32 + srow) * K + \
                                                          (k0) + schunk * 8),                 \
          (__attribute__((address_space(3))) void*)(&As[bufi][(it * 256 + tid) * 8]), 16, 0, 0); \
    }                                                                                         \
    _Pragma("unroll") for (int it = 0; it < BN / 32; ++it) {                                  \
      __builtin_amdgcn_global_load_lds(                                                       \
          (const __attribute__((address_space(1))) void*)(B + (size_t)(col0 + it * 32 + srow) * K + \
                                                          (k0) + schunk * 8),                 \
          (__attribute__((address_space(3))) void*)(&Bs[bufi][(it * 256 + tid) * 8]), 16, 0, 0); \
    }                                                                                         \
  }

  STAGE(0, kbeg)
  for (int k = 0; k < niter; ++k) {
    __syncthreads();
    if (k + 1 < niter) STAGE((k + 1) & 1, kbeg + ((k + 1) << 6))
    const __hip_bfloat16* as = As[k & 1];
    const __hip_bfloat16* bs = Bs[k & 1];
#pragma unroll
    for (int kk = 0; kk < 2; ++kk) {
      const int ch = ((kk * 4 + q) ^ (r & 7)) * 8;
      bf16x8 af[4], bfr[NC];
#pragma unroll
      for (int t = 0; t < 4; ++t)
        af[t] = *(const bf16x8*)(as + (wm * 64 + t * 16 + r) * 64 + ch);
#pragma unroll
      for (int c = 0; c < NC; ++c)
        bfr[c] = *(const bf16x8*)(bs + (wn * 16 * NC + c * 16 + r) * 64 + ch);
#pragma unroll
      for (int tm = 0; tm < 4; ++tm)
#pragma unroll
        for (int tn = 0; tn < NC; ++tn)
          acc[tm][tn] = __builtin_amdgcn_mfma_f32_16x16x32_bf16(af[tm], bfr[tn], acc[tm][tn], 0, 0, 0);
    }
  }
#undef STAGE
  float* dst = (float*)(SPLITX ? (kbeg > 0 ? C1v : C0v) : C0v);
  // C/D layout: col = lane&15, row = (lane>>4)*4 + reg   [guide §3, m89-verified]
#pragma unroll
  for (int tm = 0; tm < 4; ++tm) {
    int gr0 = row0 + wm * 64 + tm * 16 + q * 4;
#pragma unroll
    for (int tn = 0; tn < NC; ++tn) {
      int gc = col0 + wn * 16 * NC + tn * 16 + r;
#pragma unroll
      for (int p = 0; p < 4; ++p) {
        float vv = acc[tm][tn][p];
        if (RELU) vv = fmaxf(vv, 0.f);
        if (OUT_BF16) {
          ((__hip_bfloat16*)C0v)[(size_t)(gr0 + p) * N + gc] = __float2bfloat16(vv);
        } else {
          dst[(size_t)(gr0 + p) * N + gc] = vv;
          if (do_mirror) dst[(size_t)gc * N + (gr0 + p)] = vv;
        }
      }
    }
  }
}

// ---------------- 3a) scan upper triangle, per-block LDS compaction ----------
// Block = one row; float4 groups fully below the diagonal are skipped.
__global__ __launch_bounds__(256) void scan_borderline(const float* __restrict__ S,
                                                       int* __restrict__ count,
                                                       int* __restrict__ list) {
  __shared__ int lqueue[2048];
  __shared__ int lcount;
  __shared__ int gbase;
  if (threadIdx.x == 0) lcount = 0;
  __syncthreads();
  const int row = blockIdx.x;
  const int base_idx = row * 2048;
#pragma unroll
  for (int t = 0; t < 2; ++t) {
    int col = t * 1024 + threadIdx.x * 4;
    if (col + 4 <= row) continue;  // whole group below diagonal
    int idx = base_idx + col;
    float4 v = *(const float4*)(S + idx);
    float vv[4] = {v.x, v.y, v.z, v.w};
#pragma unroll
    for (int u = 0; u < 4; ++u) {
      int j = col + u;
      if (j >= row && fabsf(vv[u] - 0.1f) < WINDOW) {
        int p = atomicAdd(&lcount, 1);  // LDS atomic
        lqueue[p] = idx + u;
      }
    }
  }
  __syncthreads();
  if (threadIdx.x == 0) gbase = atomicAdd(count, lcount);
  __syncthreads();
  int n = lcount, g0 = gbase;
  for (int k = threadIdx.x; k < n; k += 256) {
    int pos = g0 + k;
    if (pos < LIST_CAP) list[pos] = lqueue[k];
  }
}

// ---------------- 3b) exact f32 repair, pipelined xj prefetch ----------------
__global__ void repair_borderline(float* __restrict__ S, const int* __restrict__ count,
                                  const int* __restrict__ list, const float* __restrict__ xpt,
                                  const float* __restrict__ Wpt, const float* __restrict__ norms) {
  const int lane = threadIdx.x & 63;
  const int wid = (blockIdx.x * 256 + threadIdx.x) >> 6;
  const int nw = gridDim.x * 4;
  int n = *count;
  if (n > LIST_CAP) n = LIST_CAP;
  const int chunk = (n + nw - 1) / nw;
  int k0 = wid * chunk;
  int k1 = k0 + chunk < n ? k0 + chunk : n;
  if (k0 >= k1) return;
  int e = list[k0];
  int i = e >> 11, j = e & 2047;
  float xiv[5], xjv[5];
  {
    const float* xi = xpt + i * EPT;
    const float* xj = xpt + j * EPT;
#pragma unroll
    for (int t = 0; t < 5; ++t) {
      int idx = lane + 64 * t;
      xiv[t] = idx < EPT ? xi[idx] : 0.f;
      xjv[t] = idx < EPT ? xj[idx] : 0.f;
    }
  }
  int cur_i = i;
  for (int k = k0; k < k1; ++k) {
    int en = (k + 1 < k1) ? list[k + 1] : e;
    int in2 = en >> 11, jn = en & 2047;
    const float* xjp = xpt + jn * EPT;
    float xjn[5];
#pragma unroll
    for (int t = 0; t < 5; ++t) {
      int idx = lane + 64 * t;
      xjn[t] = idx < EPT ? xjp[idx] : 0.f;
    }
    float pre[5];
#pragma unroll
    for (int t = 0; t < 5; ++t) pre[t] = xiv[t] * xjv[t];
    float accv = 0.f;
#pragma unroll
    for (int h = 0; h < H_DIM; ++h) {
      float ph = 0.f;
#pragma unroll
      for (int t = 0; t < 5; ++t) {
        int idx = lane + 64 * t;
        if (idx < EPT) {
          float w = Wpt[h * EPT + idx];
          float w2 = w * w;
          ph += pre[t] * (w2 * w2);  // w^4 inline
        }
      }
      float invn = 1.f / (norms[i * H_DIM + h] * norms[j * H_DIM + h]);
      accv += ph * invn;
    }
#pragma unroll
    for (int o = 32; o >= 1; o >>= 1) accv += __shfl_xor(accv, o, 64);
    if (lane == 0) {
      float val = accv * (1.f / 16.f);
      S[(size_t)i * L_DIM + j] = val;
      S[(size_t)j * L_DIM + i] = val;  // symmetric twin
    }
    if (in2 != cur_i) {
      const float* xi = xpt + in2 * EPT;
#pragma unroll
      for (int t = 0; t < 5; ++t) {
        int idx = lane + 64 * t;
        xiv[t] = idx < EPT ? xi[idx] : 0.f;
      }
      cur_i = in2;
    }
    i = in2;
    j = jn;
    e = en;
#pragma unroll
    for (int t = 0; t < 5; ++t) xjv[t] = xjn[t];
  }
}

// ------- 4) post: softmax->adj  +  label cast  +  W0/W1 transpose -----------
// grid 6656: [0,2048) softmax rows; [2048,6144) cast; [6144,6656) transpose.
__global__ __launch_bounds__(256) void post_kernel(const float* __restrict__ S,
                                                   __hip_bfloat16* __restrict__ adj,
                                                   const float* __restrict__ label,
                                                   __hip_bfloat16* __restrict__ Lbf,
                                                   const float* __restrict__ W0,
                                                   const float* __restrict__ W1,
                                                   __hip_bfloat16* __restrict__ W0t,
                                                   __hip_bfloat16* __restrict__ W1t) {
  __shared__ float red[4];
  __shared__ float tile[32][33];
  const int b = blockIdx.x;
  const int tid = threadIdx.x;
  if (b < 2048) {
    const int row = b;
    const float* s = S + (size_t)row * L_DIM;
    float m = -1e30f;
    for (int j = tid; j < L_DIM; j += 256) {
      float v = s[j];
      if (v >= 0.1f && v > m) m = v;
    }
#pragma unroll
    for (int o = 32; o >= 1; o >>= 1) m = fmaxf(m, __shfl_xor(m, o, 64));
    if ((tid & 63) == 0) red[tid >> 6] = m;
    __syncthreads();
    m = fmaxf(fmaxf(red[0], red[1]), fmaxf(red[2], red[3]));
    float sum = 0.f;
    for (int j = tid; j < L_DIM; j += 256) {
      float v = s[j];
      if (v >= 0.1f) sum += __expf(v - m);
    }
#pragma unroll
    for (int o = 32; o >= 1; o >>= 1) sum += __shfl_xor(sum, o, 64);
    __syncthreads();
    if ((tid & 63) == 0) red[tid >> 6] = sum;
    __syncthreads();
    sum = red[0] + red[1] + red[2] + red[3];
    float inv = 1.f / sum;
    for (int j = tid; j < L_DIM; j += 256) {
      float v = s[j];
      float a = (v >= 0.1f) ? __expf(v - m) * inv : 0.f;
      adj[(size_t)row * L_DIM + j] = __float2bfloat16(a);
    }
    return;
  }
  if (b < 6144) {
    int i = (b - 2048) * 256 + tid;
    Lbf[i] = __float2bfloat16(label[i]);
    return;
  }
  int local = b - 6144;
  const bool first = local < 256;
  const float* src = first ? W0 : W1;
  __hip_bfloat16* dst = first ? W0t : W1t;
  int rem = local & 255;
  int c0 = (rem & 15) * 32, r0 = (rem >> 4) * 32;
  int tx = tid & 31, ty = tid >> 5;
  for (int i2 = ty; i2 < 32; i2 += 8) tile[i2][tx] = src[(size_t)(r0 + i2) * 512 + c0 + tx];
  __syncthreads();
  for (int i2 = ty; i2 < 32; i2 += 8)
    dst[(size_t)(c0 + i2) * 512 + r0 + tx] = __float2bfloat16(tile[tx][i2]);
}

// ---------------- split-K combiners (R14-proven) ----------------
__global__ void combine_relu_bf16(const float* __restrict__ P0, const float* __restrict__ P1,
                                  __hip_bfloat16* __restrict__ X) {
  int i = blockIdx.x * 256 + threadIdx.x;
  float4 a = ((const float4*)P0)[i];
  float4 b = ((const float4*)P1)[i];
  __hip_bfloat16 o0 = __float2bfloat16(fmaxf(a.x + b.x, 0.f));
  __hip_bfloat16 o1 = __float2bfloat16(fmaxf(a.y + b.y, 0.f));
  __hip_bfloat16 o2 = __float2bfloat16(fmaxf(a.z + b.z, 0.f));
  __hip_bfloat16 o3 = __float2bfloat16(fmaxf(a.w + b.w, 0.f));
  X[4 * i + 0] = o0;
  X[4 * i + 1] = o1;
  X[4 * i + 2] = o2;
  X[4 * i + 3] = o3;
}

__global__ void combine_relu_f32(const float* __restrict__ P0, const float* __restrict__ P1,
                                 float* __restrict__ X) {
  int i = blockIdx.x * 256 + threadIdx.x;
  float4 a = ((const float4*)P0)[i];
  float4 b = ((const float4*)P1)[i];
  float4 v;
  v.x = fmaxf(a.x + b.x, 0.f);
  v.y = fmaxf(a.y + b.y, 0.f);
  v.z = fmaxf(a.z + b.z, 0.f);
  v.w = fmaxf(a.w + b.w, 0.f);
  ((float4*)X)[i] = v;
}

extern "C" void kernel_launch(void* const* d_in, const int* in_sizes, int n_in, void* d_out,
                              int out_size, void* d_ws, size_t ws_size, hipStream_t stream) {
  const float* label = (const float*)d_in[0];  // [2048,512]
  const float* xpt = (const float*)d_in[1];    // [2048,300]
  const float* Wpt = (const float*)d_in[2];    // [16,300]
  const float* W0 = (const float*)d_in[3];     // [512,512]
  const float* W1 = (const float*)d_in[4];     // [512,512]
  float* out = (float*)d_out;                  // [2048,512]

  // ---- layout (peak 44.96MB; ws >= 53.4MB proven by R12's split run) ----
  char* ws = (char*)d_ws;
  __hip_bfloat16* Y = (__hip_bfloat16*)ws;              // [0, 19,660,800) live thru gram
  float* S = (float*)(ws + 19660800);                   // [19,660,800, 36,438,016)
  float* norms = (float*)(ws + 36438016);               // 128KB -> ends 36,569,088
  float* P0 = (float*)(ws + 36569088);                  // 4MB partial
  float* P1 = (float*)(ws + 40763392);                  // 4MB -> ends 44,957,696
  int* bl_count = (int*)(ws + 44957696);                // outside all live regions
  int* bl_list = (int*)(ws + 9437696);                  // dead-Y region, written post-gram
  __hip_bfloat16* adj = (__hip_bfloat16*)ws;            // [0, 8,388,608) after softmax
  // GCN temporaries in the dead [8.39MB, 17.83MB) window (bl_list dead after repair):
  __hip_bfloat16* Lbf = (__hip_bfloat16*)(ws + 8388608);    // 2MB
  __hip_bfloat16* W0t = (__hip_bfloat16*)(ws + 10485760);   // 0.5MB
  __hip_bfloat16* W1t = (__hip_bfloat16*)(ws + 11010048);   // 0.5MB
  __hip_bfloat16* T0t = (__hip_bfloat16*)(ws + 11534336);   // 2MB [512x2048]
  __hip_bfloat16* X1 = (__hip_bfloat16*)(ws + 13631488);    // 2MB [2048x512]
  __hip_bfloat16* T1t = (__hip_bfloat16*)(ws + 15728640);   // 2MB -> ends 17,825,792

  compute_y_kernel<<<8192, 256, 0, stream>>>(xpt, Wpt, Y, norms);
  hipMemsetAsync(bl_count, 0, 4, stream);
  // S = Y Y^T: R14-proven 64x64 triangle+mirror, grid (32,32), 528 live blocks
  gemm_bt<64, 64, false, false, true, false><<<dim3(32, 32), 256, 0, stream>>>(Y, Y, S, nullptr, 2048, 2048, KDIM);
  scan_borderline<<<2048, 256, 0, stream>>>(S, bl_count, bl_list);
  repair_borderline<<<2048, 256, 0, stream>>>(S, bl_count, bl_list, xpt, Wpt, norms);
  // softmax -> adj + label cast + W transposes (one launch)
  post_kernel<<<6656, 256, 0, stream>>>(S, adj, label, Lbf, W0, W1, W0t, W1t);
  // T0t = (label@W0)^T = W0t * Lbf^T   [512 x 2048]
  gemm_bt<64, 64, false, true, false, false><<<dim3(32, 8), 256, 0, stream>>>(W0t, Lbf, T0t, nullptr, 512, 2048, 512);
  // X1 = relu(adj @ T0): split-K=2 (x-folded, 512 blocks) -> P0/P1, combine
  gemm_bt<64, 64, false, false, false, true><<<dim3(16, 32), 256, 0, stream>>>(adj, T0t, P0, P1, 2048, 512, 2048);
  combine_relu_bf16<<<1024, 256, 0, stream>>>(P0, P1, X1);
  // T1t = (X1@W1)^T = W1t * X1^T   [512 x 2048]
  gemm_bt<64, 64, false, true, false, false><<<dim3(32, 8), 256, 0, stream>>>(W1t, X1, T1t, nullptr, 512, 2048, 512);
  // out = relu(adj @ T1): split-K=2 -> P0/P1, combine into d_out
  gemm_bt<64, 64, false, false, false, true><<<dim3(16, 32), 256, 0, stream>>>(adj, T1t, P0, P1, 2048, 512, 2048);
  combine_relu_f32<<<1024, 256, 0, stream>>>(P0, P1, out);
}

// Round 17
// 205.116 us; speedup vs baseline: 1.3208x; 1.2748x over previous
//
#include <hip/hip_runtime.h>
#include <hip/hip_bf16.h>

// L=2048, E=512, E_PT=300, H=16. All inputs f32. Output f32 [2048,512].
//
// R17 = R16 (proven 261us) + scan/repair FUSION:
//  - one row-owned kernel: block i scans row i (j>=i, float4, below-diag
//    groups skipped) into an LDS queue, then its 4 waves repair the queued
//    entries in-place (exact f32, w^4 inline), writing S[i][j] + S[j][i].
//    Race-free: pair (i,j) owned solely by block i; mirror S[j][i] has
//    column i<j which block j never reads (scans only j'>=j).
//  - kills: scan dispatch, memset dispatch, bl_count/bl_list buffers.
// 12 -> 10 dispatches. Gram + GCN chain = R16 verbatim (each proven).

typedef __attribute__((ext_vector_type(8))) short bf16x8;
typedef __attribute__((ext_vector_type(4))) float f32x4;

#define L_DIM 2048
#define EPT 300
#define H_DIM 16
#define KDIM 4800
#define WINDOW 5.5e-4f

// ---------------- 1) Y + norms ----------------
__global__ void compute_y_kernel(const float* __restrict__ xpt,
                                 const float* __restrict__ Wpt,
                                 __hip_bfloat16* __restrict__ Y,
                                 float* __restrict__ norms) {
  int gw = (blockIdx.x * 256 + threadIdx.x) >> 6;  // wave id = (i,h) pair
  int lane = threadIdx.x & 63;
  int i = gw >> 4, h = gw & 15;
  const float* x = xpt + i * EPT;
  const float* w = Wpt + h * EPT;
  float v[5];
  float ss = 0.f;
#pragma unroll
  for (int t = 0; t < 5; ++t) {
    int e = lane + 64 * t;
    float val = 0.f;
    if (e < EPT) {
      float we = w[e];
      val = x[e] * we * we;
    }
    v[t] = val;
    ss += val * val;
  }
#pragma unroll
  for (int o = 32; o >= 1; o >>= 1) ss += __shfl_xor(ss, o, 64);
  float n = fmaxf(sqrtf(ss), 1e-12f);
  if (lane == 0) norms[i * H_DIM + h] = n;
  float scale = 0.25f / n;  // 1/(norm*sqrt(H))
#pragma unroll
  for (int t = 0; t < 5; ++t) {
    int e = lane + 64 * t;
    if (e < EPT) Y[(size_t)i * KDIM + h * EPT + e] = __float2bfloat16(v[t] * scale);
  }
}

// ---------------- 2) bt-GEMM: C = A * B^T (R14/R16-proven) ----------------
template <int BM, int BN, bool RELU, bool OUT_BF16, bool MIRROR, bool SPLITX>
__global__ __launch_bounds__(256) void gemm_bt(const __hip_bfloat16* __restrict__ A,
                                               const __hip_bfloat16* __restrict__ B,
                                               void* __restrict__ C0v, void* __restrict__ C1v,
                                               int M, int N, int K) {
  constexpr int WMG = BM / 64;
  constexpr int WNG = 4 / WMG;
  constexpr int NC = BN / (16 * WNG);
  int bx = blockIdx.x;
  int kbeg = 0, kend = K;
  if (SPLITX) {
    const int xhalf = gridDim.x >> 1;
    const int khalf = ((K >> 1) + 63) & ~63;
    if (bx >= xhalf) {
      bx -= xhalf;
      kbeg = khalf;
    } else {
      kend = khalf;
    }
  }
  const int row0 = blockIdx.y * BM, col0 = bx * BN;
  if (MIRROR && col0 + BN <= row0) return;  // fully below diagonal
  const bool do_mirror = MIRROR && (col0 > row0);
  __shared__ __attribute__((aligned(16))) __hip_bfloat16 As[2][BM * 64];
  __shared__ __attribute__((aligned(16))) __hip_bfloat16 Bs[2][BN * 64];
  const int tid = threadIdx.x;
  const int lane = tid & 63;
  const int wave = tid >> 6;
  const int wm = wave / WNG, wn = wave % WNG;
  const int r = lane & 15, q = lane >> 4;
  const int srow = tid >> 3;
  const int schunk = (tid & 7) ^ (srow & 7);

  f32x4 acc[4][NC];
#pragma unroll
  for (int a = 0; a < 4; ++a)
#pragma unroll
    for (int b = 0; b < NC; ++b) {
      f32x4 z = {0.f, 0.f, 0.f, 0.f};
      acc[a][b] = z;
    }

  const int niter = (kend - kbeg) >> 6;

#define STAGE(bufi, k0)                                                                       \
  {                                                                                           \
    _Pragma("unroll") for (int it = 0; it < BM / 32; ++it) {                                  \
      __builtin_amdgcn_global_load_lds(                                                       \
          (const __attribute__((address_space(1))) void*)(A + (size_t)(row0 + it * 32 + srow) * K + \
                                                          (k0) + schunk * 8),                 \
          (__attribute__((address_space(3))) void*)(&As[bufi][(it * 256 + tid) * 8]), 16, 0, 0); \
    }                                                                                         \
    _Pragma("unroll") for (int it = 0; it < BN / 32; ++it) {                                  \
      __builtin_amdgcn_global_load_lds(                                                       \
          (const __attribute__((address_space(1))) void*)(B + (size_t)(col0 + it * 32 + srow) * K + \
                                                          (k0) + schunk * 8),                 \
          (__attribute__((address_space(3))) void*)(&Bs[bufi][(it * 256 + tid) * 8]), 16, 0, 0); \
    }                                                                                         \
  }

  STAGE(0, kbeg)
  for (int k = 0; k < niter; ++k) {
    __syncthreads();
    if (k + 1 < niter) STAGE((k + 1) & 1, kbeg + ((k + 1) << 6))
    const __hip_bfloat16* as = As[k & 1];
    const __hip_bfloat16* bs = Bs[k & 1];
#pragma unroll
    for (int kk = 0; kk < 2; ++kk) {
      const int ch = ((kk * 4 + q) ^ (r & 7)) * 8;
      bf16x8 af[4], bfr[NC];
#pragma unroll
      for (int t = 0; t < 4; ++t)
        af[t] = *(const bf16x8*)(as + (wm * 64 + t * 16 + r) * 64 + ch);
#pragma unroll
      for (int c = 0; c < NC; ++c)
        bfr[c] = *(const bf16x8*)(bs + (wn * 16 * NC + c * 16 + r) * 64 + ch);
#pragma unroll
      for (int tm = 0; tm < 4; ++tm)
#pragma unroll
        for (int tn = 0; tn < NC; ++tn)
          acc[tm][tn] = __builtin_amdgcn_mfma_f32_16x16x32_bf16(af[tm], bfr[tn], acc[tm][tn], 0, 0, 0);
    }
  }
#undef STAGE
  float* dst = (float*)(SPLITX ? (kbeg > 0 ? C1v : C0v) : C0v);
  // C/D layout: col = lane&15, row = (lane>>4)*4 + reg   [guide §3, m89-verified]
#pragma unroll
  for (int tm = 0; tm < 4; ++tm) {
    int gr0 = row0 + wm * 64 + tm * 16 + q * 4;
#pragma unroll
    for (int tn = 0; tn < NC; ++tn) {
      int gc = col0 + wn * 16 * NC + tn * 16 + r;
#pragma unroll
      for (int p = 0; p < 4; ++p) {
        float vv = acc[tm][tn][p];
        if (RELU) vv = fmaxf(vv, 0.f);
        if (OUT_BF16) {
          ((__hip_bfloat16*)C0v)[(size_t)(gr0 + p) * N + gc] = __float2bfloat16(vv);
        } else {
          dst[(size_t)(gr0 + p) * N + gc] = vv;
          if (do_mirror) dst[(size_t)gc * N + (gr0 + p)] = vv;
        }
      }
    }
  }
}

// ------- 3) fused scan+repair: block = row i; LDS queue; 4 waves repair -----
__global__ __launch_bounds__(256) void scan_repair(float* __restrict__ S,
                                                   const float* __restrict__ xpt,
                                                   const float* __restrict__ Wpt,
                                                   const float* __restrict__ norms) {
  __shared__ int lqueue[2048];
  __shared__ int lcount;
  if (threadIdx.x == 0) lcount = 0;
  __syncthreads();
  const int row = blockIdx.x;
  const int base_idx = row * 2048;
#pragma unroll
  for (int t = 0; t < 2; ++t) {
    int col = t * 1024 + threadIdx.x * 4;
    if (col + 4 <= row) continue;  // whole float4 group below diagonal
    float4 v = *(const float4*)(S + base_idx + col);
    float vv[4] = {v.x, v.y, v.z, v.w};
#pragma unroll
    for (int u = 0; u < 4; ++u) {
      int j = col + u;
      if (j >= row && fabsf(vv[u] - 0.1f) < WINDOW) {
        int p = atomicAdd(&lcount, 1);  // LDS atomic
        lqueue[p] = j;
      }
    }
  }
  __syncthreads();
  const int n = lcount;
  if (n == 0) return;
  const int lane = threadIdx.x & 63;
  const int wave = threadIdx.x >> 6;
  const int i = row;
  float xiv[5];
  {
    const float* xi = xpt + i * EPT;
#pragma unroll
    for (int t = 0; t < 5; ++t) {
      int idx = lane + 64 * t;
      xiv[t] = idx < EPT ? xi[idx] : 0.f;
    }
  }
  for (int k = wave; k < n; k += 4) {  // waves take entries round-robin
    int j = lqueue[k];
    const float* xj = xpt + j * EPT;
    float pre[5];
#pragma unroll
    for (int t = 0; t < 5; ++t) {
      int idx = lane + 64 * t;
      pre[t] = idx < EPT ? xiv[t] * xj[idx] : 0.f;
    }
    float accv = 0.f;
#pragma unroll
    for (int h = 0; h < H_DIM; ++h) {
      float ph = 0.f;
#pragma unroll
      for (int t = 0; t < 5; ++t) {
        int idx = lane + 64 * t;
        if (idx < EPT) {
          float w = Wpt[h * EPT + idx];
          float w2 = w * w;
          ph += pre[t] * (w2 * w2);  // w^4 inline
        }
      }
      accv += ph * (1.f / (norms[i * H_DIM + h] * norms[j * H_DIM + h]));
    }
#pragma unroll
    for (int o = 32; o >= 1; o >>= 1) accv += __shfl_xor(accv, o, 64);
    if (lane == 0) {
      float val = accv * (1.f / 16.f);
      S[(size_t)i * L_DIM + j] = val;
      S[(size_t)j * L_DIM + i] = val;  // mirror: column i<j, unread by block j
    }
  }
}

// ------- 4) post: softmax->adj  +  label cast  +  W0/W1 transpose -----------
// grid 6656: [0,2048) softmax rows; [2048,6144) cast; [6144,6656) transpose.
__global__ __launch_bounds__(256) void post_kernel(const float* __restrict__ S,
                                                   __hip_bfloat16* __restrict__ adj,
                                                   const float* __restrict__ label,
                                                   __hip_bfloat16* __restrict__ Lbf,
                                                   const float* __restrict__ W0,
                                                   const float* __restrict__ W1,
                                                   __hip_bfloat16* __restrict__ W0t,
                                                   __hip_bfloat16* __restrict__ W1t) {
  __shared__ float red[4];
  __shared__ float tile[32][33];
  const int b = blockIdx.x;
  const int tid = threadIdx.x;
  if (b < 2048) {
    const int row = b;
    const float* s = S + (size_t)row * L_DIM;
    float m = -1e30f;
    for (int j = tid; j < L_DIM; j += 256) {
      float v = s[j];
      if (v >= 0.1f && v > m) m = v;
    }
#pragma unroll
    for (int o = 32; o >= 1; o >>= 1) m = fmaxf(m, __shfl_xor(m, o, 64));
    if ((tid & 63) == 0) red[tid >> 6] = m;
    __syncthreads();
    m = fmaxf(fmaxf(red[0], red[1]), fmaxf(red[2], red[3]));
    float sum = 0.f;
    for (int j = tid; j < L_DIM; j += 256) {
      float v = s[j];
      if (v >= 0.1f) sum += __expf(v - m);
    }
#pragma unroll
    for (int o = 32; o >= 1; o >>= 1) sum += __shfl_xor(sum, o, 64);
    __syncthreads();
    if ((tid & 63) == 0) red[tid >> 6] = sum;
    __syncthreads();
    sum = red[0] + red[1] + red[2] + red[3];
    float inv = 1.f / sum;
    for (int j = tid; j < L_DIM; j += 256) {
      float v = s[j];
      float a = (v >= 0.1f) ? __expf(v - m) * inv : 0.f;
      adj[(size_t)row * L_DIM + j] = __float2bfloat16(a);
    }
    return;
  }
  if (b < 6144) {
    int i = (b - 2048) * 256 + tid;
    Lbf[i] = __float2bfloat16(label[i]);
    return;
  }
  int local = b - 6144;
  const bool first = local < 256;
  const float* src = first ? W0 : W1;
  __hip_bfloat16* dst = first ? W0t : W1t;
  int rem = local & 255;
  int c0 = (rem & 15) * 32, r0 = (rem >> 4) * 32;
  int tx = tid & 31, ty = tid >> 5;
  for (int i2 = ty; i2 < 32; i2 += 8) tile[i2][tx] = src[(size_t)(r0 + i2) * 512 + c0 + tx];
  __syncthreads();
  for (int i2 = ty; i2 < 32; i2 += 8)
    dst[(size_t)(c0 + i2) * 512 + r0 + tx] = __float2bfloat16(tile[tx][i2]);
}

// ---------------- split-K combiners (R14-proven) ----------------
__global__ void combine_relu_bf16(const float* __restrict__ P0, const float* __restrict__ P1,
                                  __hip_bfloat16* __restrict__ X) {
  int i = blockIdx.x * 256 + threadIdx.x;
  float4 a = ((const float4*)P0)[i];
  float4 b = ((const float4*)P1)[i];
  __hip_bfloat16 o0 = __float2bfloat16(fmaxf(a.x + b.x, 0.f));
  __hip_bfloat16 o1 = __float2bfloat16(fmaxf(a.y + b.y, 0.f));
  __hip_bfloat16 o2 = __float2bfloat16(fmaxf(a.z + b.z, 0.f));
  __hip_bfloat16 o3 = __float2bfloat16(fmaxf(a.w + b.w, 0.f));
  X[4 * i + 0] = o0;
  X[4 * i + 1] = o1;
  X[4 * i + 2] = o2;
  X[4 * i + 3] = o3;
}

__global__ void combine_relu_f32(const float* __restrict__ P0, const float* __restrict__ P1,
                                 float* __restrict__ X) {
  int i = blockIdx.x * 256 + threadIdx.x;
  float4 a = ((const float4*)P0)[i];
  float4 b = ((const float4*)P1)[i];
  float4 v;
  v.x = fmaxf(a.x + b.x, 0.f);
  v.y = fmaxf(a.y + b.y, 0.f);
  v.z = fmaxf(a.z + b.z, 0.f);
  v.w = fmaxf(a.w + b.w, 0.f);
  ((float4*)X)[i] = v;
}

extern "C" void kernel_launch(void* const* d_in, const int* in_sizes, int n_in, void* d_out,
                              int out_size, void* d_ws, size_t ws_size, hipStream_t stream) {
  const float* label = (const float*)d_in[0];  // [2048,512]
  const float* xpt = (const float*)d_in[1];    // [2048,300]
  const float* Wpt = (const float*)d_in[2];    // [16,300]
  const float* W0 = (const float*)d_in[3];     // [512,512]
  const float* W1 = (const float*)d_in[4];     // [512,512]
  float* out = (float*)d_out;                  // [2048,512]

  // ---- layout (peak 44.96MB; ws >= 53.4MB proven by R12's split run) ----
  char* ws = (char*)d_ws;
  __hip_bfloat16* Y = (__hip_bfloat16*)ws;              // [0, 19,660,800) live thru gram
  float* S = (float*)(ws + 19660800);                   // [19,660,800, 36,438,016)
  float* norms = (float*)(ws + 36438016);               // 128KB -> ends 36,569,088
  float* P0 = (float*)(ws + 36569088);                  // 4MB partial
  float* P1 = (float*)(ws + 40763392);                  // 4MB -> ends 44,957,696
  __hip_bfloat16* adj = (__hip_bfloat16*)ws;            // [0, 8,388,608) after softmax
  // GCN temporaries in the dead-Y window [8.39MB, 17.83MB):
  __hip_bfloat16* Lbf = (__hip_bfloat16*)(ws + 8388608);    // 2MB
  __hip_bfloat16* W0t = (__hip_bfloat16*)(ws + 10485760);   // 0.5MB
  __hip_bfloat16* W1t = (__hip_bfloat16*)(ws + 11010048);   // 0.5MB
  __hip_bfloat16* T0t = (__hip_bfloat16*)(ws + 11534336);   // 2MB [512x2048]
  __hip_bfloat16* X1 = (__hip_bfloat16*)(ws + 13631488);    // 2MB [2048x512]
  __hip_bfloat16* T1t = (__hip_bfloat16*)(ws + 15728640);   // 2MB -> ends 17,825,792

  compute_y_kernel<<<8192, 256, 0, stream>>>(xpt, Wpt, Y, norms);
  // S = Y Y^T: R14-proven 64x64 triangle+mirror, grid (32,32), 528 live blocks
  gemm_bt<64, 64, false, false, true, false><<<dim3(32, 32), 256, 0, stream>>>(Y, Y, S, nullptr, 2048, 2048, KDIM);
  // fused borderline scan + exact-f32 repair (row-owned; no global list)
  scan_repair<<<2048, 256, 0, stream>>>(S, xpt, Wpt, norms);
  // softmax -> adj + label cast + W transposes (one launch)
  post_kernel<<<6656, 256, 0, stream>>>(S, adj, label, Lbf, W0, W1, W0t, W1t);
  // T0t = (label@W0)^T = W0t * Lbf^T   [512 x 2048]
  gemm_bt<64, 64, false, true, false, false><<<dim3(32, 8), 256, 0, stream>>>(W0t, Lbf, T0t, nullptr, 512, 2048, 512);
  // X1 = relu(adj @ T0): split-K=2 (x-folded, 512 blocks) -> P0/P1, combine
  gemm_bt<64, 64, false, false, false, true><<<dim3(16, 32), 256, 0, stream>>>(adj, T0t, P0, P1, 2048, 512, 2048);
  combine_relu_bf16<<<1024, 256, 0, stream>>>(P0, P1, X1);
  // T1t = (X1@W1)^T = W1t * X1^T   [512 x 2048]
  gemm_bt<64, 64, false, true, false, false><<<dim3(32, 8), 256, 0, stream>>>(W1t, X1, T1t, nullptr, 512, 2048, 512);
  // out = relu(adj @ T1): split-K=2 -> P0/P1, combine into d_out
  gemm_bt<64, 64, false, false, false, true><<<dim3(16, 32), 256, 0, stream>>>(adj, T1t, P0, P1, 2048, 512, 2048);
  combine_relu_f32<<<1024, 256, 0, stream>>>(P0, P1, out);
}